// Round 1
// baseline (383.503 us; speedup 1.0000x reference)
//
#include <hip/hip_runtime.h>

typedef __attribute__((ext_vector_type(4))) float f32x4;
typedef __attribute__((ext_vector_type(8))) short s16x8;
typedef __attribute__((ext_vector_type(4))) int i32x4;
typedef __attribute__((ext_vector_type(4))) unsigned short u16x4;

#define NEG_INF_F (-9.0e15f)
#define LOG2E_F 1.44269504088896340736f
#define N_ROWS 8192
#define F_DIM 256

__device__ __forceinline__ unsigned short f2bf(float f) {
    unsigned int u = __builtin_bit_cast(unsigned int, f);
    u += 0x7fffu + ((u >> 16) & 1u);   // round-to-nearest-even
    return (unsigned short)(u >> 16);
}

// ------------- Kernel 1: h = x @ W^T (f32) ; hT = bf16(h)^T --------------
// grid 512 = 128 row-blocks x 4 f-blocks, 256 threads, 64KB LDS (2 blocks/CU)
__global__ __launch_bounds__(256) void k1_gemm(const float* __restrict__ x,
                                               const float* __restrict__ W,
                                               float* __restrict__ h,
                                               unsigned short* __restrict__ hT) {
    __shared__ float xT[128][64];   // k-major: xT[kk][r]
    __shared__ float wT[128][64];   // k-major: wT[kk][f]
    const int tid = threadIdx.x;
    const int rb = blockIdx.x >> 2, fbk = blockIdx.x & 3;
    const int row0 = rb * 64, f0 = fbk * 64;
    const int rs = tid >> 2, cs = tid & 3;          // staging: row, k-chunk
    const int r0 = (tid & 15) * 4, fc = (tid >> 4) * 4;  // compute: 4x4 tile
    float acc[4][4];
#pragma unroll
    for (int i = 0; i < 4; ++i)
#pragma unroll
        for (int j = 0; j < 4; ++j) acc[i][j] = 0.0f;

#pragma unroll 1
    for (int p = 0; p < 2; ++p) {               // two K panels of 128
        const int kb = p * 128;
        if (p) __syncthreads();                 // prev compute done before overwrite
        const float* xrow = x + (size_t)(row0 + rs) * F_DIM + kb + cs * 32;
        const float* wrow = W + (size_t)(f0 + rs) * F_DIM + kb + cs * 32;
#pragma unroll
        for (int i = 0; i < 8; ++i) {
            f32x4 xv = *(const f32x4*)(xrow + i * 4);
            f32x4 wv = *(const f32x4*)(wrow + i * 4);
#pragma unroll
            for (int jj = 0; jj < 4; ++jj) {
                xT[cs * 32 + i * 4 + jj][rs] = xv[jj];
                wT[cs * 32 + i * 4 + jj][rs] = wv[jj];
            }
        }
        __syncthreads();
#pragma unroll 4
        for (int kk = 0; kk < 128; ++kk) {
            f32x4 xv = *(const f32x4*)&xT[kk][r0];
            f32x4 wv = *(const f32x4*)&wT[kk][fc];
#pragma unroll
            for (int i = 0; i < 4; ++i)
#pragma unroll
                for (int j = 0; j < 4; ++j)
                    acc[i][j] = fmaf(xv[i], wv[j], acc[i][j]);
        }
    }
    // h (f32, row-major), coalesced f32x4 stores
#pragma unroll
    for (int i = 0; i < 4; ++i) {
        f32x4 hv;
        hv[0] = acc[i][0]; hv[1] = acc[i][1]; hv[2] = acc[i][2]; hv[3] = acc[i][3];
        *(f32x4*)(h + (size_t)(row0 + r0 + i) * F_DIM + f0 + fc) = hv;
    }
    // hT (bf16, [256][8192]) — 4 consecutive rows packed to 8B stores
#pragma unroll
    for (int j = 0; j < 4; ++j) {
        u16x4 t;
        t[0] = f2bf(acc[0][j]); t[1] = f2bf(acc[1][j]);
        t[2] = f2bf(acc[2][j]); t[3] = f2bf(acc[3][j]);
        *(u16x4*)(hT + (size_t)(f0 + fc + j) * N_ROWS + row0 + r0) = t;
    }
}

// ------------- Kernel 1b: s1 = h@a1, s2 = h@a2 (f32) ---------------------
__global__ __launch_bounds__(256) void k1b_s(const float* __restrict__ h,
                                             const float* __restrict__ a,
                                             float* __restrict__ s1,
                                             float* __restrict__ s2) {
    const int tid = threadIdx.x, lane = tid & 63, w = tid >> 6;
    f32x4 a1 = *(const f32x4*)(a + lane * 4);
    f32x4 a2 = *(const f32x4*)(a + 256 + lane * 4);
    const int row0 = blockIdx.x * 32 + w * 8;
#pragma unroll 1
    for (int rr = 0; rr < 8; ++rr) {
        const int row = row0 + rr;
        f32x4 hv = *(const f32x4*)(h + (size_t)row * F_DIM + lane * 4);
        float p1 = hv[0] * a1[0] + hv[1] * a1[1] + hv[2] * a1[2] + hv[3] * a1[3];
        float p2 = hv[0] * a2[0] + hv[1] * a2[1] + hv[2] * a2[2] + hv[3] * a2[3];
#pragma unroll
        for (int o = 32; o; o >>= 1) { p1 += __shfl_xor(p1, o); p2 += __shfl_xor(p2, o); }
        if (lane == 0) { s1[row] = p1; s2[row] = p2; }
    }
}

// ------------- Kernel 2: fused masked softmax + PV -----------------------
// One 64-key step: scores in MFMA A-frag layout (row = lane&15, k = (lane>>4)*8+j)
__device__ __forceinline__ void k2_step(i32x4 q0, i32x4 q1, i32x4 q2, i32x4 q3,
                                        int k0, int lane15, int kg, int koff, int fb,
                                        float si,
                                        const unsigned short* __restrict__ hT,
                                        const float* __restrict__ s2,
                                        f32x4* __restrict__ acc,
                                        float& m_run, float& l_run) {
    // B fragments (V = h), issued early so L2 latency hides under softmax VALU
    s16x8 bfr0[8], bfr1[8];
#pragma unroll
    for (int nt = 0; nt < 8; ++nt) {
        const size_t rbase = (size_t)(fb + nt * 16 + lane15) * N_ROWS;
        bfr0[nt] = *(const s16x8*)(hT + rbase + k0 + koff);
        bfr1[nt] = *(const s16x8*)(hT + rbase + k0 + 32 + koff);
    }
    f32x4 sv0 = *(const f32x4*)(s2 + k0 + koff);
    f32x4 sv1 = *(const f32x4*)(s2 + k0 + koff + 4);
    f32x4 sv2 = *(const f32x4*)(s2 + k0 + 32 + koff);
    f32x4 sv3 = *(const f32x4*)(s2 + k0 + 32 + koff + 4);

    float ev[16];
#pragma unroll
    for (int j = 0; j < 4; ++j) {
        float t0 = si + sv0[j]; t0 = fmaxf(t0, 0.2f * t0); ev[j]      = (q0[j] > 0) ? t0 : NEG_INF_F;
        float t1 = si + sv1[j]; t1 = fmaxf(t1, 0.2f * t1); ev[4 + j]  = (q1[j] > 0) ? t1 : NEG_INF_F;
        float t2 = si + sv2[j]; t2 = fmaxf(t2, 0.2f * t2); ev[8 + j]  = (q2[j] > 0) ? t2 : NEG_INF_F;
        float t3 = si + sv3[j]; t3 = fmaxf(t3, 0.2f * t3); ev[12 + j] = (q3[j] > 0) ? t3 : NEG_INF_F;
    }
    float tm = ev[0];
#pragma unroll
    for (int i = 1; i < 16; ++i) tm = fmaxf(tm, ev[i]);
    tm = fmaxf(tm, __shfl_xor(tm, 16));   // reduce across the 4 k-groups of a row
    tm = fmaxf(tm, __shfl_xor(tm, 32));
    const float m_new = fmaxf(m_run, tm);
    const bool upd = m_new > m_run;
    const float sc = exp2f((m_run - m_new) * LOG2E_F);
    float pv[16];
    float ts = 0.0f;
#pragma unroll
    for (int i = 0; i < 16; ++i) { pv[i] = exp2f((ev[i] - m_new) * LOG2E_F); ts += pv[i]; }
    ts += __shfl_xor(ts, 16);
    ts += __shfl_xor(ts, 32);
    l_run = l_run * sc + ts;
    m_run = m_new;
    if (__any(upd)) {
        // move per-row scale (held at lane==row, rows 0..15) to D-layout rows (lane>>4)*4+r
#pragma unroll
        for (int r = 0; r < 4; ++r) {
            const float scr = __shfl(sc, kg * 4 + r);
#pragma unroll
            for (int nt = 0; nt < 8; ++nt) acc[nt][r] *= scr;
        }
    }
    s16x8 af0, af1;
#pragma unroll
    for (int j = 0; j < 8; ++j) { af0[j] = (short)f2bf(pv[j]); af1[j] = (short)f2bf(pv[8 + j]); }
#pragma unroll
    for (int nt = 0; nt < 8; ++nt)
        acc[nt] = __builtin_amdgcn_mfma_f32_16x16x32_bf16(af0, bfr0[nt], acc[nt], 0, 0, 0);
#pragma unroll
    for (int nt = 0; nt < 8; ++nt)
        acc[nt] = __builtin_amdgcn_mfma_f32_16x16x32_bf16(af1, bfr1[nt], acc[nt], 0, 0, 0);
}

// grid 256 blocks x 32 rows; 4 waves = 2(row-halves) x 2(feature-halves); no LDS.
__global__ __launch_bounds__(256) void k2_attn(const int* __restrict__ adj,
                                               const unsigned short* __restrict__ hT,
                                               const float* __restrict__ s1,
                                               const float* __restrict__ s2,
                                               float* __restrict__ out) {
    const int tid = threadIdx.x;
    const int lane = tid & 63;
    const int wvi = tid >> 6;
    const int wm = wvi & 1, wn = wvi >> 1;
    const int lane15 = lane & 15, kg = lane >> 4, koff = kg * 8;
    const int row0 = (int)blockIdx.x * 32;
    const int mrow = row0 + wm * 16 + lane15;
    const int fb = wn * 128;
    const float si = s1[mrow];
    const int* __restrict__ arow = adj + (size_t)mrow * N_ROWS;

    f32x4 acc[8];
#pragma unroll
    for (int nt = 0; nt < 8; ++nt) { f32x4 z = {0.f, 0.f, 0.f, 0.f}; acc[nt] = z; }
    float m_run = NEG_INF_F, l_run = 0.0f;

    i32x4 A0, A1, A2, A3, B0, B1, B2, B3;
    A0 = *(const i32x4*)(arow + koff);
    A1 = *(const i32x4*)(arow + koff + 4);
    A2 = *(const i32x4*)(arow + 32 + koff);
    A3 = *(const i32x4*)(arow + 32 + koff + 4);

#pragma unroll 1
    for (int it = 0; it < 64; ++it) {
        const int k0 = it * 128;
        {   // prefetch keys [k0+64, k0+128)
            const int kp = k0 + 64;
            B0 = *(const i32x4*)(arow + kp + koff);
            B1 = *(const i32x4*)(arow + kp + koff + 4);
            B2 = *(const i32x4*)(arow + kp + 32 + koff);
            B3 = *(const i32x4*)(arow + kp + 32 + koff + 4);
        }
        k2_step(A0, A1, A2, A3, k0, lane15, kg, koff, fb, si, hT, s2, acc, m_run, l_run);
        {   // prefetch keys [k0+128, k0+192) (clamped on last iter)
            const int kp = (k0 + 128 < N_ROWS) ? (k0 + 128) : 0;
            A0 = *(const i32x4*)(arow + kp + koff);
            A1 = *(const i32x4*)(arow + kp + koff + 4);
            A2 = *(const i32x4*)(arow + kp + 32 + koff);
            A3 = *(const i32x4*)(arow + kp + 32 + koff + 4);
        }
        k2_step(B0, B1, B2, B3, k0 + 64, lane15, kg, koff, fb, si, hT, s2, acc, m_run, l_run);
    }

    const float linv = 1.0f / l_run;
#pragma unroll
    for (int r = 0; r < 4; ++r) {
        const float lr = __shfl(linv, kg * 4 + r);
        const int orow = row0 + wm * 16 + kg * 4 + r;
        float* orow_p = out + (size_t)orow * F_DIM + fb + lane15;
#pragma unroll
        for (int nt = 0; nt < 8; ++nt) orow_p[nt * 16] = acc[nt][r] * lr;
    }
}

extern "C" void kernel_launch(void* const* d_in, const int* in_sizes, int n_in,
                              void* d_out, int out_size, void* d_ws, size_t ws_size,
                              hipStream_t stream) {
    (void)in_sizes; (void)n_in; (void)out_size; (void)ws_size;
    const float* x  = (const float*)d_in[0];
    const int*  adj = (const int*)d_in[1];
    const float* W  = (const float*)d_in[2];
    const float* a  = (const float*)d_in[3];
    float* out = (float*)d_out;
    char* ws = (char*)d_ws;
    unsigned short* hT = (unsigned short*)ws;               // 4 MB  [256][8192] bf16
    float* h  = (float*)(ws + (4 << 20));                   // 8 MB  [8192][256] f32
    float* s1 = (float*)(ws + (12 << 20));                  // 32 KB
    float* s2 = (float*)(ws + (12 << 20) + 32768);          // 32 KB

    k1_gemm<<<512, 256, 0, stream>>>(x, W, h, hT);
    k1b_s<<<256, 256, 0, stream>>>(h, a, s1, s2);
    k2_attn<<<256, 256, 0, stream>>>(adj, hT, s1, s2, out);
}